// Round 1
// baseline (381.754 us; speedup 1.0000x reference)
//
#include <hip/hip_runtime.h>
#include <math.h>

#define BB 8
#define PP 100
#define QQ 10000

// ---------------- K1: G_hat (majority vote, first-max tie) + count_d ----------------
__global__ void k1_ghat(const int* __restrict__ M, unsigned char* __restrict__ ghat,
                        unsigned char* __restrict__ cd, double* __restrict__ acc) {
    int tid = blockIdx.x * blockDim.x + threadIdx.x;
    if (blockIdx.x == 0 && threadIdx.x < 2) acc[threadIdx.x] = 0.0;  // zero loss accumulators
    if (tid >= BB * QQ) return;
    int b = tid / QQ, q = tid - b * QQ;
    const int* Mb = M + b * PP * QQ + q;
    int c0 = 0, c1 = 0, c2 = 0, c3 = 0;
    #pragma unroll 4
    for (int p = 0; p < PP; p++) {
        int m = Mb[p * QQ];
        c0 += (m == 0); c1 += (m == 1); c2 += (m == 2); c3 += (m == 3);
    }
    int g = 0, best = c0;
    if (c1 > best) { g = 1; best = c1; }
    if (c2 > best) { g = 2; best = c2; }
    if (c3 > best) { g = 3; best = c3; }
    ghat[tid] = (unsigned char)g;
    cd[tid] = (unsigned char)best;   // count of majority class == sum_p Mc
}

// ---------------- K4: bin_d = stable-argsort quantile bins of count_d ----------------
// one block per b, 128 threads; chunked histogram + exclusive scans -> stable rank
__global__ void k4_bind(const unsigned char* __restrict__ cd, unsigned char* __restrict__ bind) {
    int b = blockIdx.x, t = threadIdx.x;
    __shared__ unsigned short h[128][101];
    __shared__ int pfx[101];
    for (int v = 0; v < 101; v++) h[t][v] = 0;
    const int CH = (QQ + 127) / 128;           // 79
    int q0 = t * CH, q1 = min(q0 + CH, QQ);
    const unsigned char* c = cd + b * QQ;
    __syncthreads();
    for (int q = q0; q < q1; q++) h[t][c[q]]++;
    __syncthreads();
    for (int v = t; v < 101; v += 128) {       // exclusive scan per value across chunks
        int run = 0;
        for (int tt = 0; tt < 128; tt++) { int x = h[tt][v]; h[tt][v] = (unsigned short)run; run += x; }
        pfx[v] = run;                          // total count of value v
    }
    __syncthreads();
    if (t == 0) { int run = 0; for (int v = 0; v < 101; v++) { int x = pfx[v]; pfx[v] = run; run += x; } }
    __syncthreads();
    unsigned char* bd = bind + b * QQ;
    for (int q = q0; q < q1; q++) {
        int v = c[q];
        int r = pfx[v] + (int)h[t][v];         // stable rank
        h[t][v]++;
        bd[q] = (unsigned char)(r / 2000);
    }
}

// ---------------- K2: count_a + a_k bin counts + first-layer worker partial pa ----------------
__global__ void k2_counts(const int* __restrict__ M, const unsigned char* __restrict__ ghat,
                          const unsigned char* __restrict__ bind, int* __restrict__ count_a,
                          float* __restrict__ pa, const float* __restrict__ cW1) {
    int blk = blockIdx.x;                      // 0..799
    int b = blk / PP, p = blk - b * PP;
    int t = threadIdx.x;                       // 256
    const int* Mb = M + (b * PP + p) * QQ;
    const unsigned char* gh = ghat + b * QQ;
    const unsigned char* bd = bind + b * QQ;
    int cnt = 0, k0 = 0, k1 = 0, k2 = 0, k3 = 0, k4 = 0;
    for (int q = t; q < QQ; q += 256) {
        int mc = (Mb[q] == (int)gh[q]);
        int bb = bd[q];
        cnt += mc;
        k0 += mc & (bb == 0); k1 += mc & (bb == 1); k2 += mc & (bb == 2);
        k3 += mc & (bb == 3); k4 += mc & (bb == 4);
    }
    __shared__ int red[4][6];
    int w = t >> 6, l = t & 63;
    int v[6] = {cnt, k0, k1, k2, k3, k4};
    #pragma unroll
    for (int i = 0; i < 6; i++) {
        int x = v[i];
        #pragma unroll
        for (int off = 32; off > 0; off >>= 1) x += __shfl_down(x, off);
        if (l == 0) red[w][i] = x;
    }
    __syncthreads();
    if (t == 0) {
        int s[6];
        #pragma unroll
        for (int i = 0; i < 6; i++) s[i] = red[0][i] + red[1][i] + red[2][i] + red[3][i];
        count_a[b * PP + p] = s[0];
        float fa0 = (float)s[0] / 10000.0f;    // a_list
        float fk[5];
        #pragma unroll
        for (int k = 0; k < 5; k++) fk[k] = (float)s[1 + k] / 2000.0f;  // a_k
        float* par = pa + (b * PP + p) * 12;
        #pragma unroll
        for (int j = 0; j < 10; j++) {
            float sj = fa0 * cW1[j];           // cW1 row 0
            #pragma unroll
            for (int k = 0; k < 5; k++) sj = fmaf(fk[k], cW1[(1 + k) * 10 + j], sj);
            par[j] = sj;
        }
        par[10] = 0.f; par[11] = 0.f;
    }
}

// ---------------- K3: bin_a = stable rank of count_a (O(P^2)) ----------------
__global__ void k3_bina(const int* __restrict__ count_a, unsigned char* __restrict__ bina) {
    int b = blockIdx.x, p = threadIdx.x;       // 128 threads
    __shared__ int ca[PP];
    if (p < PP) ca[p] = count_a[b * PP + p];
    __syncthreads();
    if (p < PP) {
        int me = ca[p], r = 0;
        for (int pp = 0; pp < PP; pp++) {
            int cc = ca[pp];
            r += (cc < me) || (cc == me && pp < p);
        }
        bina[b * PP + p] = (unsigned char)(r / 20);
    }
}

// ---------------- K6: fused main kernel ----------------
// 256 threads = 64 q * 4 p-splits (lane&3 = split t, also = class id in tail)
__launch_bounds__(256)
__global__ void k6_main(const int* __restrict__ M, const int* __restrict__ G_true,
    const unsigned char* __restrict__ ghat, const unsigned char* __restrict__ cd,
    const unsigned char* __restrict__ bina, const float* __restrict__ pa,
    const float* __restrict__ cW1, const float* __restrict__ cb1,
    const float* __restrict__ cW2, const float* __restrict__ cb2,
    const float* __restrict__ cW3, const float* __restrict__ cb3,
    const float* __restrict__ cW4, const float* __restrict__ cb4,
    const float* __restrict__ rW1, const float* __restrict__ rb1,
    const float* __restrict__ rW2, const float* __restrict__ rb2,
    const float* __restrict__ rW3, const float* __restrict__ rb3,
    const float* __restrict__ rW4, const float* __restrict__ rb4,
    double* __restrict__ acc)
{
    __shared__ float pa_s[PP][12];
    __shared__ float rw1_s[PP][16];
    __shared__ float w2_s[10][12], w3_s[10][12];
    __shared__ float w1d_s[6][12];
    __shared__ float rw2_s[15][16], rw3_s[15][16];
    __shared__ float w4_s[12], b2_s[12], b3_s[12], cb1_s[12];
    __shared__ float rw4_s[16], rb1_s[16], rb2_s[16], rb3_s[16];
    __shared__ unsigned char bina_s[PP];
    __shared__ float wred[4][2];

    int b = blockIdx.y;
    int tid = threadIdx.x;

    for (int i = tid; i < PP * 12; i += 256) pa_s[i / 12][i % 12] = pa[b * PP * 12 + i];
    for (int i = tid; i < PP * 16; i += 256) { int r = i >> 4, c = i & 15; rw1_s[r][c] = (c < 15) ? rW1[r * 15 + c] : 0.f; }
    for (int i = tid; i < 120; i += 256) { int r = i / 12, c = i % 12;
        w2_s[r][c] = (c < 10) ? cW2[r * 10 + c] : 0.f;
        w3_s[r][c] = (c < 10) ? cW3[r * 10 + c] : 0.f; }
    for (int i = tid; i < 240; i += 256) { int r = i >> 4, c = i & 15;
        rw2_s[r][c] = (c < 15) ? rW2[r * 15 + c] : 0.f;
        rw3_s[r][c] = (c < 15) ? rW3[r * 15 + c] : 0.f; }
    if (tid < 12) {
        w4_s[tid]  = (tid < 10) ? cW4[tid] : 0.f;
        b2_s[tid]  = (tid < 10) ? cb2[tid] : 0.f;
        b3_s[tid]  = (tid < 10) ? cb3[tid] : 0.f;
        cb1_s[tid] = (tid < 10) ? cb1[tid] : 0.f;
    }
    if (tid >= 16 && tid < 32) { int j = tid - 16; rw4_s[j] = (j < 15) ? rW4[j] : 0.f; }
    if (tid >= 32 && tid < 48) { int j = tid - 32; rb1_s[j] = (j < 15) ? rb1[j] : 0.f; }
    if (tid >= 48 && tid < 64) { int j = tid - 48; rb2_s[j] = (j < 15) ? rb2[j] : 0.f; }
    if (tid >= 64 && tid < 80) { int j = tid - 64; rb3_s[j] = (j < 15) ? rb3[j] : 0.f; }
    if (tid >= 80 && tid < 140) { int j = tid - 80; w1d_s[j / 10][j % 10] = cW1[60 + j]; }
    if (tid >= 140 && tid < 240) bina_s[tid - 140] = bina[b * PP + (tid - 140)];
    float b4v = cb4[0], rb4v = rb4[0];
    __syncthreads();

    int qi = tid >> 2;
    int t = tid & 3;
    int q = blockIdx.x * 64 + qi;
    float lc = 0.f, lrv = 0.f;
    bool act = (q < QQ);

    if (act) {
        int bq = b * QQ + q;
        int g = (int)ghat[bq];
        int gt = G_true[bq];
        const int* Mb = M + b * PP * QQ + q;
        int p0 = t * 25;

        // ---- pass 1: d_k counts + pack M 2-bit ----
        int dc0 = 0, dc1 = 0, dc2 = 0, dc3 = 0, dc4 = 0;
        unsigned long long mp = 0ULL;
        #pragma unroll 5
        for (int i = 0; i < 25; i++) {
            int m = Mb[(p0 + i) * QQ];
            mp |= (unsigned long long)m << (2 * i);
            int mc = (m == g);
            int ba = (int)bina_s[p0 + i];
            dc0 += mc & (ba == 0); dc1 += mc & (ba == 1); dc2 += mc & (ba == 2);
            dc3 += mc & (ba == 3); dc4 += mc & (ba == 4);
        }
        dc0 += __shfl_xor(dc0, 1); dc0 += __shfl_xor(dc0, 2);
        dc1 += __shfl_xor(dc1, 1); dc1 += __shfl_xor(dc1, 2);
        dc2 += __shfl_xor(dc2, 1); dc2 += __shfl_xor(dc2, 2);
        dc3 += __shfl_xor(dc3, 1); dc3 += __shfl_xor(dc3, 2);
        dc4 += __shfl_xor(dc4, 1); dc4 += __shfl_xor(dc4, 2);

        float dlist = (float)cd[bq] / 100.0f;
        float dk0 = dc0 / 20.0f, dk1 = dc1 / 20.0f, dk2 = dc2 / 20.0f, dk3 = dc3 / 20.0f, dk4 = dc4 / 20.0f;
        float pd[10];
        #pragma unroll
        for (int j = 0; j < 10; j++) {
            float s = cb1_s[j];
            s = fmaf(dlist, w1d_s[0][j], s);
            s = fmaf(dk0, w1d_s[1][j], s);
            s = fmaf(dk1, w1d_s[2][j], s);
            s = fmaf(dk2, w1d_s[3][j], s);
            s = fmaf(dk3, w1d_s[4][j], s);
            s = fmaf(dk4, w1d_s[5][j], s);
            pd[j] = s;
        }

        // ---- pass 2: cor-MLP per worker + loss_cor + U-projection accumulators ----
        float S0[15], T0[15], T1[15], T2[15], T3[15];
        #pragma unroll
        for (int j = 0; j < 15; j++) { S0[j] = 0.f; T0[j] = 0.f; T1[j] = 0.f; T2[j] = 0.f; T3[j] = 0.f; }

        for (int i = 0; i < 25; i++) {
            int p = p0 + i;
            int m = (int)((mp >> (2 * i)) & 3ULL);
            float h1[10], h2[10], h3[10];
            #pragma unroll
            for (int j = 0; j < 10; j++) h1[j] = fmaxf(pa_s[p][j] + pd[j], 0.0f);
            #pragma unroll
            for (int j = 0; j < 10; j++) h2[j] = b2_s[j];
            #pragma unroll
            for (int j1 = 0; j1 < 10; j1++) {
                float x = h1[j1];
                #pragma unroll
                for (int j2 = 0; j2 < 10; j2++) h2[j2] = fmaf(x, w2_s[j1][j2], h2[j2]);
            }
            #pragma unroll
            for (int j = 0; j < 10; j++) { h2[j] = fmaxf(h2[j], 0.0f); h3[j] = b3_s[j]; }
            #pragma unroll
            for (int j1 = 0; j1 < 10; j1++) {
                float x = h2[j1];
                #pragma unroll
                for (int j2 = 0; j2 < 10; j2++) h3[j2] = fmaf(x, w3_s[j1][j2], h3[j2]);
            }
            float xx = b4v;
            #pragma unroll
            for (int j = 0; j < 10; j++) xx = fmaf(fmaxf(h3[j], 0.0f), w4_s[j], xx);
            float Y = 1.0f / (1.0f + expf(-xx));
            float yc = fminf(fmaxf(Y, 1e-12f), 1.0f - 1e-12f);
            lc += logf((m == gt) ? yc : 1.0f - yc);
            float c0v = (1.0f - Y) / 3.0f;
            float dlv = Y - c0v;
            float e0 = (m == 0) ? dlv : 0.0f;
            float e1 = (m == 1) ? dlv : 0.0f;
            float e2 = (m == 2) ? dlv : 0.0f;
            float e3 = (m == 3) ? dlv : 0.0f;
            #pragma unroll
            for (int j = 0; j < 15; j++) {
                float wv = rw1_s[p][j];
                S0[j] = fmaf(c0v, wv, S0[j]);
                T0[j] = fmaf(e0, wv, T0[j]);
                T1[j] = fmaf(e1, wv, T1[j]);
                T2[j] = fmaf(e2, wv, T2[j]);
                T3[j] = fmaf(e3, wv, T3[j]);
            }
        }

        // reduce across the 4 p-split lanes
        #pragma unroll
        for (int j = 0; j < 15; j++) {
            S0[j] += __shfl_xor(S0[j], 1); S0[j] += __shfl_xor(S0[j], 2);
            T0[j] += __shfl_xor(T0[j], 1); T0[j] += __shfl_xor(T0[j], 2);
            T1[j] += __shfl_xor(T1[j], 1); T1[j] += __shfl_xor(T1[j], 2);
            T2[j] += __shfl_xor(T2[j], 1); T2[j] += __shfl_xor(T2[j], 2);
            T3[j] += __shfl_xor(T3[j], 1); T3[j] += __shfl_xor(T3[j], 2);
        }

        // ---- tail: each lane evaluates class a = t of the ref-MLP ----
        float g1[15], g2[15];
        #pragma unroll
        for (int j = 0; j < 15; j++) {
            float Ta = (t == 0) ? T0[j] : ((t == 1) ? T1[j] : ((t == 2) ? T2[j] : T3[j]));
            g1[j] = tanhf(S0[j] + Ta + rb1_s[j]);
        }
        #pragma unroll
        for (int j = 0; j < 15; j++) g2[j] = rb2_s[j];
        #pragma unroll
        for (int j1 = 0; j1 < 15; j1++) {
            float x = g1[j1];
            #pragma unroll
            for (int j2 = 0; j2 < 15; j2++) g2[j2] = fmaf(x, rw2_s[j1][j2], g2[j2]);
        }
        #pragma unroll
        for (int j = 0; j < 15; j++) { g2[j] = tanhf(g2[j]); g1[j] = rb3_s[j]; }
        #pragma unroll
        for (int j1 = 0; j1 < 15; j1++) {
            float x = g2[j1];
            #pragma unroll
            for (int j2 = 0; j2 < 15; j2++) g1[j2] = fmaf(x, rw3_s[j1][j2], g1[j2]);
        }
        float z = rb4v;
        #pragma unroll
        for (int j = 0; j < 15; j++) z = fmaf(tanhf(g1[j]), rw4_s[j], z);

        // softmax over the 4 class-lanes
        float zm = fmaxf(z, __shfl_xor(z, 1)); zm = fmaxf(zm, __shfl_xor(zm, 2));
        float ez = expf(z - zm);
        float es = ez + __shfl_xor(ez, 1); es += __shfl_xor(es, 2);
        float prob = ez / es;
        // log_softmax of probs (double softmax per reference)
        float pm = fmaxf(prob, __shfl_xor(prob, 1)); pm = fmaxf(pm, __shfl_xor(pm, 2));
        float ep = expf(prob - pm);
        float eps_ = ep + __shfl_xor(ep, 1); eps_ += __shfl_xor(eps_, 2);
        float lse = pm + logf(eps_);
        float lp = prob - lse;
        float sel = (t == gt) ? lp : 0.f;
        sel += __shfl_xor(sel, 1); sel += __shfl_xor(sel, 2);
        if (t == 0) lrv = sel;
    }

    // block reduce -> f64 atomics
    float v1 = lc, v2 = lrv;
    #pragma unroll
    for (int off = 32; off > 0; off >>= 1) { v1 += __shfl_down(v1, off); v2 += __shfl_down(v2, off); }
    if ((tid & 63) == 0) { wred[tid >> 6][0] = v1; wred[tid >> 6][1] = v2; }
    __syncthreads();
    if (tid == 0) {
        float s1 = wred[0][0] + wred[1][0] + wred[2][0] + wred[3][0];
        float s2 = wred[0][1] + wred[1][1] + wred[2][1] + wred[3][1];
        atomicAdd(&acc[0], (double)s1);
        atomicAdd(&acc[1], (double)s2);
    }
}

// ---------------- K7: finalize ----------------
__global__ void k7_final(const double* __restrict__ acc, float* __restrict__ out) {
    if (threadIdx.x == 0) {
        out[0] = (float)(-acc[0] / (double)(BB * PP * QQ));
        out[1] = (float)(-acc[1] / (double)(BB * QQ));
    }
}

extern "C" void kernel_launch(void* const* d_in, const int* in_sizes, int n_in,
                              void* d_out, int out_size, void* d_ws, size_t ws_size,
                              hipStream_t stream) {
    const int*   M      = (const int*)d_in[0];
    const int*   G_true = (const int*)d_in[1];
    const float* cW1 = (const float*)d_in[2];  const float* cb1 = (const float*)d_in[3];
    const float* cW2 = (const float*)d_in[4];  const float* cb2 = (const float*)d_in[5];
    const float* cW3 = (const float*)d_in[6];  const float* cb3 = (const float*)d_in[7];
    const float* cW4 = (const float*)d_in[8];  const float* cb4 = (const float*)d_in[9];
    const float* rW1 = (const float*)d_in[10]; const float* rb1 = (const float*)d_in[11];
    const float* rW2 = (const float*)d_in[12]; const float* rb2 = (const float*)d_in[13];
    const float* rW3 = (const float*)d_in[14]; const float* rb3 = (const float*)d_in[15];
    const float* rW4 = (const float*)d_in[16]; const float* rb4 = (const float*)d_in[17];

    char* ws = (char*)d_ws;
    double* acc            = (double*)ws;                    // 16 B
    float* pa              = (float*)(ws + 16);              // 800*12*4 = 38400
    int* count_a           = (int*)(ws + 38416);             // 3200
    unsigned char* ghat    = (unsigned char*)(ws + 41616);   // 80000
    unsigned char* cd      = (unsigned char*)(ws + 121616);  // 80000
    unsigned char* bind    = (unsigned char*)(ws + 201616);  // 80000
    unsigned char* bina    = (unsigned char*)(ws + 281616);  // 800

    k1_ghat<<<(BB * QQ + 255) / 256, 256, 0, stream>>>(M, ghat, cd, acc);
    k4_bind<<<BB, 128, 0, stream>>>(cd, bind);
    k2_counts<<<BB * PP, 256, 0, stream>>>(M, ghat, bind, count_a, pa, cW1);
    k3_bina<<<BB, 128, 0, stream>>>(count_a, bina);
    dim3 g6((QQ + 63) / 64, BB);
    k6_main<<<g6, 256, 0, stream>>>(M, G_true, ghat, cd, bina, pa,
        cW1, cb1, cW2, cb2, cW3, cb3, cW4, cb4,
        rW1, rb1, rW2, rb2, rW3, rb3, rW4, rb4, acc);
    k7_final<<<1, 1, 0, stream>>>(acc, (float*)d_out);
}

// Round 2
// 331.545 us; speedup vs baseline: 1.1514x; 1.1514x over previous
//
#include <hip/hip_runtime.h>
#include <math.h>

#define BB 8
#define PP 100
#define QQ 10000

__device__ __forceinline__ float frcp(float x) { return __builtin_amdgcn_rcpf(x); }
__device__ __forceinline__ float ftanh(float x) {
    // (e^2x - 1)/(e^2x + 1); saturates correctly at +/-1 via inf/0
    float e2 = __expf(2.0f * x);
    return 1.0f - 2.0f * frcp(e2 + 1.0f);
}

// ---------------- K1: G_hat (majority vote, first-max tie) + count_d ----------------
__global__ void k1_ghat(const int* __restrict__ M, unsigned char* __restrict__ ghat,
                        unsigned char* __restrict__ cd, double* __restrict__ acc) {
    int tid = blockIdx.x * blockDim.x + threadIdx.x;
    if (blockIdx.x == 0 && threadIdx.x < 2) acc[threadIdx.x] = 0.0;  // zero loss accumulators
    if (tid >= BB * QQ) return;
    int b = tid / QQ, q = tid - b * QQ;
    const int* Mb = M + b * PP * QQ + q;
    int c0 = 0, c1 = 0, c2 = 0, c3 = 0;
    #pragma unroll 4
    for (int p = 0; p < PP; p++) {
        int m = Mb[p * QQ];
        c0 += (m == 0); c1 += (m == 1); c2 += (m == 2); c3 += (m == 3);
    }
    int g = 0, best = c0;
    if (c1 > best) { g = 1; best = c1; }
    if (c2 > best) { g = 2; best = c2; }
    if (c3 > best) { g = 3; best = c3; }
    ghat[tid] = (unsigned char)g;
    cd[tid] = (unsigned char)best;
}

// ---------------- K4: bin_d = stable-argsort quantile bins of count_d ----------------
__global__ void k4_bind(const unsigned char* __restrict__ cd, unsigned char* __restrict__ bind) {
    int b = blockIdx.x, t = threadIdx.x;
    __shared__ unsigned short h[128][101];
    __shared__ int pfx[101];
    for (int v = 0; v < 101; v++) h[t][v] = 0;
    const int CH = (QQ + 127) / 128;           // 79
    int q0 = t * CH, q1 = min(q0 + CH, QQ);
    const unsigned char* c = cd + b * QQ;
    __syncthreads();
    for (int q = q0; q < q1; q++) h[t][c[q]]++;
    __syncthreads();
    for (int v = t; v < 101; v += 128) {
        int run = 0;
        for (int tt = 0; tt < 128; tt++) { int x = h[tt][v]; h[tt][v] = (unsigned short)run; run += x; }
        pfx[v] = run;
    }
    __syncthreads();
    if (t == 0) { int run = 0; for (int v = 0; v < 101; v++) { int x = pfx[v]; pfx[v] = run; run += x; } }
    __syncthreads();
    unsigned char* bd = bind + b * QQ;
    for (int q = q0; q < q1; q++) {
        int v = c[q];
        int r = pfx[v] + (int)h[t][v];
        h[t][v]++;
        bd[q] = (unsigned char)(r / 2000);
    }
}

// ---------------- K2: count_a + a_k bin counts + first-layer worker partial pa ----------------
__global__ void k2_counts(const int* __restrict__ M, const unsigned char* __restrict__ ghat,
                          const unsigned char* __restrict__ bind, int* __restrict__ count_a,
                          float* __restrict__ pa, const float* __restrict__ cW1) {
    int blk = blockIdx.x;
    int b = blk / PP, p = blk - b * PP;
    int t = threadIdx.x;
    const int* Mb = M + (b * PP + p) * QQ;
    const unsigned char* gh = ghat + b * QQ;
    const unsigned char* bd = bind + b * QQ;
    int cnt = 0, k0 = 0, k1 = 0, k2 = 0, k3 = 0, k4 = 0;
    for (int q = t; q < QQ; q += 256) {
        int mc = (Mb[q] == (int)gh[q]);
        int bb = bd[q];
        cnt += mc;
        k0 += mc & (bb == 0); k1 += mc & (bb == 1); k2 += mc & (bb == 2);
        k3 += mc & (bb == 3); k4 += mc & (bb == 4);
    }
    __shared__ int red[4][6];
    int w = t >> 6, l = t & 63;
    int v[6] = {cnt, k0, k1, k2, k3, k4};
    #pragma unroll
    for (int i = 0; i < 6; i++) {
        int x = v[i];
        #pragma unroll
        for (int off = 32; off > 0; off >>= 1) x += __shfl_down(x, off);
        if (l == 0) red[w][i] = x;
    }
    __syncthreads();
    if (t == 0) {
        int s[6];
        #pragma unroll
        for (int i = 0; i < 6; i++) s[i] = red[0][i] + red[1][i] + red[2][i] + red[3][i];
        count_a[b * PP + p] = s[0];
        float fa0 = (float)s[0] / 10000.0f;
        float fk[5];
        #pragma unroll
        for (int k = 0; k < 5; k++) fk[k] = (float)s[1 + k] / 2000.0f;
        float* par = pa + (b * PP + p) * 12;
        #pragma unroll
        for (int j = 0; j < 10; j++) {
            float sj = fa0 * cW1[j];
            #pragma unroll
            for (int k = 0; k < 5; k++) sj = fmaf(fk[k], cW1[(1 + k) * 10 + j], sj);
            par[j] = sj;
        }
        par[10] = 0.f; par[11] = 0.f;
    }
}

// ---------------- K3: bin_a = stable rank of count_a (O(P^2)) ----------------
__global__ void k3_bina(const int* __restrict__ count_a, unsigned char* __restrict__ bina) {
    int b = blockIdx.x, p = threadIdx.x;
    __shared__ int ca[PP];
    if (p < PP) ca[p] = count_a[b * PP + p];
    __syncthreads();
    if (p < PP) {
        int me = ca[p], r = 0;
        for (int pp = 0; pp < PP; pp++) {
            int cc = ca[pp];
            r += (cc < me) || (cc == me && pp < p);
        }
        bina[b * PP + p] = (unsigned char)(r / 20);
    }
}

// ---- cor-MLP for two workers sharing one pass over the weight rows ----
__device__ __forceinline__ void cor_mlp2(
    const float* __restrict__ paA, const float* __restrict__ paB,
    const float* __restrict__ pd,
    const float (*__restrict__ w2)[12], const float (*__restrict__ w3)[12],
    const float* __restrict__ b2, const float* __restrict__ b3,
    const float* __restrict__ w4, float b4, float& Ya, float& Yb)
{
    float h1a[10], h1b[10], h2a[10], h2b[10];
    #pragma unroll
    for (int j = 0; j < 10; j++) {
        h1a[j] = fmaxf(paA[j] + pd[j], 0.f);
        h1b[j] = fmaxf(paB[j] + pd[j], 0.f);
        h2a[j] = b2[j]; h2b[j] = b2[j];
    }
    #pragma unroll
    for (int j1 = 0; j1 < 10; j1++) {
        float wrow[12];
        const float4* wr = (const float4*)w2[j1];
        ((float4*)wrow)[0] = wr[0]; ((float4*)wrow)[1] = wr[1]; ((float4*)wrow)[2] = wr[2];
        float xa = h1a[j1], xb = h1b[j1];
        #pragma unroll
        for (int j2 = 0; j2 < 10; j2++) {
            h2a[j2] = fmaf(xa, wrow[j2], h2a[j2]);
            h2b[j2] = fmaf(xb, wrow[j2], h2b[j2]);
        }
    }
    float h3a[10], h3b[10];
    #pragma unroll
    for (int j = 0; j < 10; j++) {
        h2a[j] = fmaxf(h2a[j], 0.f); h2b[j] = fmaxf(h2b[j], 0.f);
        h3a[j] = b3[j]; h3b[j] = b3[j];
    }
    #pragma unroll
    for (int j1 = 0; j1 < 10; j1++) {
        float wrow[12];
        const float4* wr = (const float4*)w3[j1];
        ((float4*)wrow)[0] = wr[0]; ((float4*)wrow)[1] = wr[1]; ((float4*)wrow)[2] = wr[2];
        float xa = h2a[j1], xb = h2b[j1];
        #pragma unroll
        for (int j2 = 0; j2 < 10; j2++) {
            h3a[j2] = fmaf(xa, wrow[j2], h3a[j2]);
            h3b[j2] = fmaf(xb, wrow[j2], h3b[j2]);
        }
    }
    float xa = b4, xb = b4;
    #pragma unroll
    for (int j = 0; j < 10; j++) {
        float w = w4[j];
        xa = fmaf(fmaxf(h3a[j], 0.f), w, xa);
        xb = fmaf(fmaxf(h3b[j], 0.f), w, xb);
    }
    Ya = frcp(1.0f + __expf(-xa));
    Yb = frcp(1.0f + __expf(-xb));
}

__device__ __forceinline__ void cor_mlp1(
    const float* __restrict__ paA, const float* __restrict__ pd,
    const float (*__restrict__ w2)[12], const float (*__restrict__ w3)[12],
    const float* __restrict__ b2, const float* __restrict__ b3,
    const float* __restrict__ w4, float b4, float& Ya)
{
    float h1a[10], h2a[10];
    #pragma unroll
    for (int j = 0; j < 10; j++) { h1a[j] = fmaxf(paA[j] + pd[j], 0.f); h2a[j] = b2[j]; }
    #pragma unroll
    for (int j1 = 0; j1 < 10; j1++) {
        float xa = h1a[j1];
        #pragma unroll
        for (int j2 = 0; j2 < 10; j2++) h2a[j2] = fmaf(xa, w2[j1][j2], h2a[j2]);
    }
    float h3a[10];
    #pragma unroll
    for (int j = 0; j < 10; j++) { h2a[j] = fmaxf(h2a[j], 0.f); h3a[j] = b3[j]; }
    #pragma unroll
    for (int j1 = 0; j1 < 10; j1++) {
        float xa = h2a[j1];
        #pragma unroll
        for (int j2 = 0; j2 < 10; j2++) h3a[j2] = fmaf(xa, w3[j1][j2], h3a[j2]);
    }
    float xa = b4;
    #pragma unroll
    for (int j = 0; j < 10; j++) xa = fmaf(fmaxf(h3a[j], 0.f), w4[j], xa);
    Ya = frcp(1.0f + __expf(-xa));
}

// ---------------- K6: fused main kernel ----------------
__launch_bounds__(256)
__global__ void k6_main(const int* __restrict__ M, const int* __restrict__ G_true,
    const unsigned char* __restrict__ ghat, const unsigned char* __restrict__ cd,
    const unsigned char* __restrict__ bina, const float* __restrict__ pa,
    const float* __restrict__ cW1, const float* __restrict__ cb1,
    const float* __restrict__ cW2, const float* __restrict__ cb2,
    const float* __restrict__ cW3, const float* __restrict__ cb3,
    const float* __restrict__ cW4, const float* __restrict__ cb4,
    const float* __restrict__ rW1, const float* __restrict__ rb1,
    const float* __restrict__ rW2, const float* __restrict__ rb2,
    const float* __restrict__ rW3, const float* __restrict__ rb3,
    const float* __restrict__ rW4, const float* __restrict__ rb4,
    double* __restrict__ acc)
{
    __shared__ float pa_s[PP][12];
    __shared__ float rw1_s[PP][16];
    __shared__ float w2_s[10][12], w3_s[10][12];
    __shared__ float w1d_s[6][12];
    __shared__ float rw2_s[15][16], rw3_s[15][16];
    __shared__ float w4_s[12], b2_s[12], b3_s[12], cb1_s[12];
    __shared__ float rw4_s[16], rb1_s[16], rb2_s[16], rb3_s[16];
    __shared__ unsigned char bina_s[PP];
    __shared__ float Y_s[64][102];
    __shared__ unsigned long long cls_s[64][4];
    __shared__ float wred[4][2];

    int b = blockIdx.y;
    int tid = threadIdx.x;

    for (int i = tid; i < PP * 12; i += 256) pa_s[i / 12][i % 12] = pa[b * PP * 12 + i];
    for (int i = tid; i < PP * 16; i += 256) { int r = i >> 4, c = i & 15; rw1_s[r][c] = (c < 15) ? rW1[r * 15 + c] : 0.f; }
    for (int i = tid; i < 120; i += 256) { int r = i / 12, c = i % 12;
        w2_s[r][c] = (c < 10) ? cW2[r * 10 + c] : 0.f;
        w3_s[r][c] = (c < 10) ? cW3[r * 10 + c] : 0.f; }
    for (int i = tid; i < 240; i += 256) { int r = i >> 4, c = i & 15;
        rw2_s[r][c] = (c < 15) ? rW2[r * 15 + c] : 0.f;
        rw3_s[r][c] = (c < 15) ? rW3[r * 15 + c] : 0.f; }
    if (tid < 12) {
        w4_s[tid]  = (tid < 10) ? cW4[tid] : 0.f;
        b2_s[tid]  = (tid < 10) ? cb2[tid] : 0.f;
        b3_s[tid]  = (tid < 10) ? cb3[tid] : 0.f;
        cb1_s[tid] = (tid < 10) ? cb1[tid] : 0.f;
    }
    if (tid >= 16 && tid < 32) { int j = tid - 16; rw4_s[j] = (j < 15) ? rW4[j] : 0.f; }
    if (tid >= 32 && tid < 48) { int j = tid - 32; rb1_s[j] = (j < 15) ? rb1[j] : 0.f; }
    if (tid >= 48 && tid < 64) { int j = tid - 48; rb2_s[j] = (j < 15) ? rb2[j] : 0.f; }
    if (tid >= 64 && tid < 80) { int j = tid - 64; rb3_s[j] = (j < 15) ? rb3[j] : 0.f; }
    if (tid >= 80 && tid < 140) { int j = tid - 80; w1d_s[j / 10][j % 10] = cW1[60 + j]; }
    if (tid >= 140 && tid < 240) bina_s[tid - 140] = bina[b * PP + (tid - 140)];
    float b4v = cb4[0], rb4v = rb4[0];
    __syncthreads();

    int qi = tid >> 2;
    int t = tid & 3;
    int q = blockIdx.x * 64 + qi;
    float lc = 0.f, lrv = 0.f;
    bool act = (q < QQ);
    int gt = 0;

    // ================= phase A: per-worker cor-MLP, stage Y + classes =================
    if (act) {
        int bq = b * QQ + q;
        int g = (int)ghat[bq];
        gt = G_true[bq];
        const int* Mb = M + b * PP * QQ + q;
        int p0 = t * 25;

        // pass 1: d_k counts + pack M 2-bit
        int dc0 = 0, dc1 = 0, dc2 = 0, dc3 = 0, dc4 = 0;
        unsigned long long mp = 0ULL;
        #pragma unroll 5
        for (int i = 0; i < 25; i++) {
            int m = Mb[(p0 + i) * QQ];
            mp |= (unsigned long long)m << (2 * i);
            int mc = (m == g);
            int ba = (int)bina_s[p0 + i];
            dc0 += mc & (ba == 0); dc1 += mc & (ba == 1); dc2 += mc & (ba == 2);
            dc3 += mc & (ba == 3); dc4 += mc & (ba == 4);
        }
        cls_s[qi][t] = mp;
        dc0 += __shfl_xor(dc0, 1); dc0 += __shfl_xor(dc0, 2);
        dc1 += __shfl_xor(dc1, 1); dc1 += __shfl_xor(dc1, 2);
        dc2 += __shfl_xor(dc2, 1); dc2 += __shfl_xor(dc2, 2);
        dc3 += __shfl_xor(dc3, 1); dc3 += __shfl_xor(dc3, 2);
        dc4 += __shfl_xor(dc4, 1); dc4 += __shfl_xor(dc4, 2);

        float dlist = (float)cd[bq] / 100.0f;
        float dk0 = dc0 / 20.0f, dk1 = dc1 / 20.0f, dk2 = dc2 / 20.0f, dk3 = dc3 / 20.0f, dk4 = dc4 / 20.0f;
        float pd[10];
        #pragma unroll
        for (int j = 0; j < 10; j++) {
            float s = cb1_s[j];
            s = fmaf(dlist, w1d_s[0][j], s);
            s = fmaf(dk0, w1d_s[1][j], s);
            s = fmaf(dk1, w1d_s[2][j], s);
            s = fmaf(dk2, w1d_s[3][j], s);
            s = fmaf(dk3, w1d_s[4][j], s);
            s = fmaf(dk4, w1d_s[5][j], s);
            pd[j] = s;
        }

        // per-worker Y (pairs share weight-row loads)
        for (int ii = 0; ii < 24; ii += 2) {
            int pA = p0 + ii, pB = pA + 1;
            float Ya, Yb;
            cor_mlp2(pa_s[pA], pa_s[pB], pd, w2_s, w3_s, b2_s, b3_s, w4_s, b4v, Ya, Yb);
            Y_s[qi][pA] = Ya; Y_s[qi][pB] = Yb;
            int ma = (int)((mp >> (2 * ii)) & 3ULL);
            int mb2 = (int)((mp >> (2 * ii + 2)) & 3ULL);
            float yca = fminf(fmaxf(Ya, 1e-12f), 1.0f - 1e-12f);
            float ycb = fminf(fmaxf(Yb, 1e-12f), 1.0f - 1e-12f);
            lc += __logf((ma == gt) ? yca : 1.0f - yca);
            lc += __logf((mb2 == gt) ? ycb : 1.0f - ycb);
        }
        {
            int pA = p0 + 24;
            float Ya;
            cor_mlp1(pa_s[pA], pd, w2_s, w3_s, b2_s, b3_s, w4_s, b4v, Ya);
            Y_s[qi][pA] = Ya;
            int ma = (int)((mp >> 48) & 3ULL);
            float yca = fminf(fmaxf(Ya, 1e-12f), 1.0f - 1e-12f);
            lc += __logf((ma == gt) ? yca : 1.0f - yca);
        }
    }

    __syncthreads();

    // ================= phase B: class-t accumulation over all 100 workers =================
    if (act) {
        float accB[15];
        #pragma unroll
        for (int j = 0; j < 15; j++) accB[j] = rb1_s[j];

        #pragma unroll
        for (int s = 0; s < 4; s++) {
            unsigned long long mm = cls_s[qi][s];
            int pbase = s * 25;
            for (int i = 0; i < 25; i++) {
                int p = pbase + i;
                float Yv = Y_s[qi][p];
                int m = (int)((mm >> (2 * i)) & 3ULL);
                float u = (m == t) ? Yv : (1.0f - Yv) * (1.0f / 3.0f);
                float wrow[16];
                const float4* wr = (const float4*)rw1_s[p];
                ((float4*)wrow)[0] = wr[0]; ((float4*)wrow)[1] = wr[1];
                ((float4*)wrow)[2] = wr[2]; ((float4*)wrow)[3] = wr[3];
                #pragma unroll
                for (int j = 0; j < 15; j++) accB[j] = fmaf(u, wrow[j], accB[j]);
            }
        }

        // ---- tail: ref-MLP for class t ----
        float g1[15], g2[15];
        #pragma unroll
        for (int j = 0; j < 15; j++) { g1[j] = ftanh(accB[j]); g2[j] = rb2_s[j]; }
        #pragma unroll
        for (int j1 = 0; j1 < 15; j1++) {
            float wrow[16];
            const float4* wr = (const float4*)rw2_s[j1];
            ((float4*)wrow)[0] = wr[0]; ((float4*)wrow)[1] = wr[1];
            ((float4*)wrow)[2] = wr[2]; ((float4*)wrow)[3] = wr[3];
            float x = g1[j1];
            #pragma unroll
            for (int j2 = 0; j2 < 15; j2++) g2[j2] = fmaf(x, wrow[j2], g2[j2]);
        }
        #pragma unroll
        for (int j = 0; j < 15; j++) { g2[j] = ftanh(g2[j]); g1[j] = rb3_s[j]; }
        #pragma unroll
        for (int j1 = 0; j1 < 15; j1++) {
            float wrow[16];
            const float4* wr = (const float4*)rw3_s[j1];
            ((float4*)wrow)[0] = wr[0]; ((float4*)wrow)[1] = wr[1];
            ((float4*)wrow)[2] = wr[2]; ((float4*)wrow)[3] = wr[3];
            float x = g2[j1];
            #pragma unroll
            for (int j2 = 0; j2 < 15; j2++) g1[j2] = fmaf(x, wrow[j2], g1[j2]);
        }
        float z = rb4v;
        #pragma unroll
        for (int j = 0; j < 15; j++) z = fmaf(ftanh(g1[j]), rw4_s[j], z);

        // softmax over the 4 class-lanes
        float zm = fmaxf(z, __shfl_xor(z, 1)); zm = fmaxf(zm, __shfl_xor(zm, 2));
        float ez = __expf(z - zm);
        float es = ez + __shfl_xor(ez, 1); es += __shfl_xor(es, 2);
        float prob = ez * frcp(es);
        // log_softmax of probs (double softmax per reference)
        float pm = fmaxf(prob, __shfl_xor(prob, 1)); pm = fmaxf(pm, __shfl_xor(pm, 2));
        float ep = __expf(prob - pm);
        float eps_ = ep + __shfl_xor(ep, 1); eps_ += __shfl_xor(eps_, 2);
        float lse = pm + __logf(eps_);
        float lp = prob - lse;
        float sel = (t == gt) ? lp : 0.f;
        sel += __shfl_xor(sel, 1); sel += __shfl_xor(sel, 2);
        if (t == 0) lrv = sel;
    }

    // block reduce -> f64 atomics
    float v1 = lc, v2 = lrv;
    #pragma unroll
    for (int off = 32; off > 0; off >>= 1) { v1 += __shfl_down(v1, off); v2 += __shfl_down(v2, off); }
    if ((tid & 63) == 0) { wred[tid >> 6][0] = v1; wred[tid >> 6][1] = v2; }
    __syncthreads();
    if (tid == 0) {
        float s1 = wred[0][0] + wred[1][0] + wred[2][0] + wred[3][0];
        float s2 = wred[0][1] + wred[1][1] + wred[2][1] + wred[3][1];
        atomicAdd(&acc[0], (double)s1);
        atomicAdd(&acc[1], (double)s2);
    }
}

// ---------------- K7: finalize ----------------
__global__ void k7_final(const double* __restrict__ acc, float* __restrict__ out) {
    if (threadIdx.x == 0) {
        out[0] = (float)(-acc[0] / (double)(BB * PP * QQ));
        out[1] = (float)(-acc[1] / (double)(BB * QQ));
    }
}

extern "C" void kernel_launch(void* const* d_in, const int* in_sizes, int n_in,
                              void* d_out, int out_size, void* d_ws, size_t ws_size,
                              hipStream_t stream) {
    const int*   M      = (const int*)d_in[0];
    const int*   G_true = (const int*)d_in[1];
    const float* cW1 = (const float*)d_in[2];  const float* cb1 = (const float*)d_in[3];
    const float* cW2 = (const float*)d_in[4];  const float* cb2 = (const float*)d_in[5];
    const float* cW3 = (const float*)d_in[6];  const float* cb3 = (const float*)d_in[7];
    const float* cW4 = (const float*)d_in[8];  const float* cb4 = (const float*)d_in[9];
    const float* rW1 = (const float*)d_in[10]; const float* rb1 = (const float*)d_in[11];
    const float* rW2 = (const float*)d_in[12]; const float* rb2 = (const float*)d_in[13];
    const float* rW3 = (const float*)d_in[14]; const float* rb3 = (const float*)d_in[15];
    const float* rW4 = (const float*)d_in[16]; const float* rb4 = (const float*)d_in[17];

    char* ws = (char*)d_ws;
    double* acc            = (double*)ws;                    // 16 B
    float* pa              = (float*)(ws + 16);              // 800*12*4 = 38400
    int* count_a           = (int*)(ws + 38416);             // 3200
    unsigned char* ghat    = (unsigned char*)(ws + 41616);   // 80000
    unsigned char* cd      = (unsigned char*)(ws + 121616);  // 80000
    unsigned char* bind    = (unsigned char*)(ws + 201616);  // 80000
    unsigned char* bina    = (unsigned char*)(ws + 281616);  // 800

    k1_ghat<<<(BB * QQ + 255) / 256, 256, 0, stream>>>(M, ghat, cd, acc);
    k4_bind<<<BB, 128, 0, stream>>>(cd, bind);
    k2_counts<<<BB * PP, 256, 0, stream>>>(M, ghat, bind, count_a, pa, cW1);
    k3_bina<<<BB, 128, 0, stream>>>(count_a, bina);
    dim3 g6((QQ + 63) / 64, BB);
    k6_main<<<g6, 256, 0, stream>>>(M, G_true, ghat, cd, bina, pa,
        cW1, cb1, cW2, cb2, cW3, cb3, cW4, cb4,
        rW1, rb1, rW2, rb2, rW3, rb3, rW4, rb4, acc);
    k7_final<<<1, 1, 0, stream>>>(acc, (float*)d_out);
}